// Round 10
// baseline (131.232 us; speedup 1.0000x reference)
//
#include <hip/hip_runtime.h>
#include <hip/hip_bf16.h>
#include <math.h>

// Problem constants (B, N, D_IN, H, F) = (2, 2048, 512, 8, 64)
#define Bq   2
#define Nq   2048
#define DIN  512
#define Hq   8
#define Fq   64
#define NEG  0.2f

using short8 = __attribute__((ext_vector_type(8))) short;   // 8 bf16 (4 VGPRs)
using f32x4  = __attribute__((ext_vector_type(4))) float;   // MFMA C/D

__device__ inline unsigned int bf16_rne(float x) {
    unsigned int u = __float_as_uint(x);
    u += 0x7fffu + ((u >> 16) & 1u);
    return u >> 16;
}

// ---------------------------------------------------------------------------
// Kernel 1 (prep): afrag (256 blocks) + wfrag (128 blocks), R8/R9-validated.
// ---------------------------------------------------------------------------
#define AFRAG_BLOCKS 256
#define WFRAG_BLOCKS 128

__global__ __launch_bounds__(256) void prep_kernel(
    const float* __restrict__ nodes, ushort* __restrict__ Afrag,
    const float* __restrict__ W,     ushort* __restrict__ Wfrag)
{
    __shared__ __align__(16) char smem[16 * 516 * 4];   // 33 KB: max(As, Ws)
    const int bid = blockIdx.x;
    const int t   = threadIdx.x;

    if (bid < AFRAG_BLOCKS) {
        float (*As)[516] = (float(*)[516])smem;
        const int mt = bid;
        {
            const int row = t >> 4, c = t & 15;
#pragma unroll
            for (int i = 0; i < 8; i++) {
                float4 v = *(const float4*)&nodes[((size_t)mt * 16 + row) * DIN + (c + i * 16) * 4];
                *(float4*)&As[row][(c + i * 16) * 4] = v;
            }
        }
        __syncthreads();
        const int lane = t & 63, ksg = t >> 6;
        const int quad = lane >> 4, l15 = lane & 15;
#pragma unroll
        for (int k2 = 0; k2 < 4; k2++) {
            int ks = ksg * 4 + k2;
            const float* src = &As[l15][ks * 32 + quad * 8];
            float4 f0 = *(const float4*)src;
            float4 f1 = *(const float4*)(src + 4);
            uint4 pk;
            pk.x = bf16_rne(f0.x) | (bf16_rne(f0.y) << 16);
            pk.y = bf16_rne(f0.z) | (bf16_rne(f0.w) << 16);
            pk.z = bf16_rne(f1.x) | (bf16_rne(f1.y) << 16);
            pk.w = bf16_rne(f1.z) | (bf16_rne(f1.w) << 16);
            *(uint4*)(Afrag + ((size_t)(mt * 16 + ks) * 64 + lane) * 8) = pk;
        }
        return;
    }

    {
        float (*Ws)[68] = (float(*)[68])smem;
        const int id = bid - AFRAG_BLOCKS;
        const int ks = id & 15, h = id >> 4;
        {
            const int row = t >> 3, c = t & 7;
            const float* src = &W[(size_t)(ks * 32 + row) * (Hq * Fq) + h * 64 + c * 8];
            float4 v0 = *(const float4*)src;
            float4 v1 = *(const float4*)(src + 4);
            *(float4*)&Ws[row][c * 8]     = v0;
            *(float4*)&Ws[row][c * 8 + 4] = v1;
        }
        __syncthreads();
        const int lane = t & 63, nf = t >> 6;
        const int quad = lane >> 4, l15 = lane & 15;
        float f[8];
#pragma unroll
        for (int jj = 0; jj < 8; jj++) f[jj] = Ws[quad * 8 + jj][nf * 16 + l15];
        uint4 pk;
        pk.x = bf16_rne(f[0]) | (bf16_rne(f[1]) << 16);
        pk.y = bf16_rne(f[2]) | (bf16_rne(f[3]) << 16);
        pk.z = bf16_rne(f[4]) | (bf16_rne(f[5]) << 16);
        pk.w = bf16_rne(f[6]) | (bf16_rne(f[7]) << 16);
        *(uint4*)(Wfrag + (((size_t)(h * 16 + ks) * 4 + nf) * 64 + lane) * 8) = pk;
    }
}

// ---------------------------------------------------------------------------
// Kernel 2 (work): gemm (blocks [0,512)) + pack_edges (int4 MLP version) —
// both R9-validated.
// ---------------------------------------------------------------------------
#define GEMM_BLOCKS 512
#define PACK_BLOCKS 1024   // B * 64 words * 2048 rows / 256 threads

__global__ __launch_bounds__(256) void work_kernel(
    const ushort* __restrict__ Afrag, const ushort* __restrict__ Wfrag,
    const float*  __restrict__ avec,
    ushort* __restrict__ Vfrag,      // [16 bh][64 s][4 nf][64 lane][8] bf16
    float* __restrict__ el_t,        // [16][2048]
    float* __restrict__ er_t,        // [16][2048]
    const int* __restrict__ edges, unsigned int* __restrict__ ebT)
{
    const int bid = blockIdx.x;
    const int t   = threadIdx.x;

    if (bid >= GEMM_BLOCKS) {
        // ---- pack edges -> transposed bitmask ebT[b][jword(64)][i(2048)] ----
        int gid = (bid - GEMM_BLOCKS) * 256 + t;   // 0..262143
        int i = gid & 2047;
        int w = (gid >> 11) & 63;
        int b = gid >> 17;
        const int4* ep = (const int4*)(edges + (((size_t)b * Nq + i) * Nq + w * 32));
        unsigned int word = 0;
#pragma unroll
        for (int c = 0; c < 8; c++) {
            int4 v = ep[c];
            word |= (v.x != 0 ? 1u : 0u) << (c * 4);
            word |= (v.y != 0 ? 1u : 0u) << (c * 4 + 1);
            word |= (v.z != 0 ? 1u : 0u) << (c * 4 + 2);
            word |= (v.w != 0 ? 1u : 0u) << (c * 4 + 3);
        }
        ebT[((size_t)b * 64 + w) * Nq + i] = word;
        return;
    }

    // ---- gemm: R8/R9-validated body ----
    const int lane = t & 63;
    const int wv   = t >> 6;
    const int quad = lane >> 4;
    const int l15  = lane & 15;
    const int h    = bid >> 6;            // 0..7
    const int mt   = (bid & 63) * 4 + wv; // 0..255
    const int row0 = mt * 16;

    const ushort* ap = Afrag + (size_t)mt * 8192 + lane * 8;   // + ks*512
    const ushort* bp = Wfrag + (size_t)h * 32768 + lane * 8;   // + ks*2048 + nf*512

    f32x4 zero4 = {0.f, 0.f, 0.f, 0.f};
    f32x4 acc[4] = {zero4, zero4, zero4, zero4};

    short8 a0, a1, b0[4], b1[4];
    a0 = *(const short8*)(ap);
#pragma unroll
    for (int nf = 0; nf < 4; nf++) b0[nf] = *(const short8*)(bp + nf * 512);

    for (int ks = 0; ks < 16; ks += 2) {
        a1 = *(const short8*)(ap + (ks + 1) * 512);
#pragma unroll
        for (int nf = 0; nf < 4; nf++) b1[nf] = *(const short8*)(bp + (ks + 1) * 2048 + nf * 512);
#pragma unroll
        for (int nf = 0; nf < 4; nf++)
            acc[nf] = __builtin_amdgcn_mfma_f32_16x16x32_bf16(a0, b0[nf], acc[nf], 0, 0, 0);
        a0 = *(const short8*)(ap + (ks + 2) * 512);   // ks=14 -> past end: lands in Wfrag, unused
#pragma unroll
        for (int nf = 0; nf < 4; nf++) b0[nf] = *(const short8*)(bp + (ks + 2) * 2048 + nf * 512);
#pragma unroll
        for (int nf = 0; nf < 4; nf++)
            acc[nf] = __builtin_amdgcn_mfma_f32_16x16x32_bf16(a1, b1[nf], acc[nf], 0, 0, 0);
    }

    // ---- fused el/er ----
    float aL[4], aR[4];
#pragma unroll
    for (int nf = 0; nf < 4; nf++) {
        aL[nf] = avec[nf * 16 + l15];
        aR[nf] = avec[Fq + nf * 16 + l15];
    }
    const int bb = row0 >> 11;
    const int bh = bb * Hq + h;
#pragma unroll
    for (int r = 0; r < 4; r++) {
        float pl = acc[0][r] * aL[0] + acc[1][r] * aL[1] + acc[2][r] * aL[2] + acc[3][r] * aL[3];
        float pr = acc[0][r] * aR[0] + acc[1][r] * aR[1] + acc[2][r] * aR[2] + acc[3][r] * aR[3];
#pragma unroll
        for (int off = 1; off < 16; off <<= 1) {
            pl += __shfl_xor(pl, off, 64);
            pr += __shfl_xor(pr, off, 64);
        }
        if (l15 == 0) {
            int n = (row0 + quad * 4 + r) & (Nq - 1);
            el_t[(size_t)bh * Nq + n] = pl;
            er_t[(size_t)bh * Nq + n] = pr;
        }
    }

    // ---- Vfrag: C in attn B-fragment order (validated R3..R9) ----
    const int n_base = row0 & (Nq - 1);
    const int sblk   = n_base >> 5;
    const int quadp  = ((wv & 1) << 1) | (quad >> 1);
    const int jj0    = (quad & 1) * 4;
#pragma unroll
    for (int nf = 0; nf < 4; nf++) {
        unsigned int r0 = bf16_rne(acc[nf][0]), r1 = bf16_rne(acc[nf][1]);
        unsigned int r2 = bf16_rne(acc[nf][2]), r3 = bf16_rne(acc[nf][3]);
        uint2 pk;
        pk.x = r0 | (r1 << 16);
        pk.y = r2 | (r3 << 16);
        size_t off = ((((size_t)bh * 64 + sblk) * 4 + nf) * 64 + quadp * 16 + l15) * 8 + jj0;
        *(uint2*)(Vfrag + off) = pk;
    }
}

// ---------------------------------------------------------------------------
// Kernel 3: MFMA attention — GRID-BUG FIX + no-K-split restructure.
// R7-R9 launched 512 blocks against a 1024-block decomposition: batch 1 was
// NEVER computed (passed only because sigmoid(mean) ~ 0.5 matched poison).
// New shape: block = 4 waves; wave owns its OWN 16 rows and runs the FULL
// K (64 steps). 64 rows/block -> 512 blocks covers all B*N rows. Benefits:
// zero LDS combine, zero syncthreads in hot loop, no idle epilogue waves,
// Vfrag bytes/row halved (shared stream, L2-resident).
// ---------------------------------------------------------------------------
__global__ __launch_bounds__(256) void attn_kernel(
    const float* __restrict__ el_t, const float* __restrict__ er_t,
    const ushort* __restrict__ Vfrag,
    const unsigned int* __restrict__ ebT, float* __restrict__ attn)
{
    const int lane = threadIdx.x & 63;
    const int wv   = threadIdx.x >> 6;     // row-group within block, 0..3
    const int quad = lane >> 4;
    const int l15  = lane & 15;
    const int bid  = blockIdx.x;           // 512 = B*H*32
    const int it   = bid & 31;
    const int h    = (bid >> 5) & 7;
    const int b    = bid >> 8;
    const int bh   = b * Hq + h;
    const int i0   = it * 64 + wv * 16;    // this wave's 16 rows

    // ---- block-wide ermax over er_t[bh][:] ----
    __shared__ float smax[4];
    const float* errow = er_t + (size_t)bh * Nq;
    float mx = -INFINITY;
#pragma unroll
    for (int ii = 0; ii < 8; ii++) mx = fmaxf(mx, errow[threadIdx.x + ii * 256]);
#pragma unroll
    for (int off = 32; off > 0; off >>= 1) mx = fmaxf(mx, __shfl_xor(mx, off, 64));
    if (lane == 0) smax[wv] = mx;
    __syncthreads();
    const float emax = fmaxf(fmaxf(smax[0], smax[1]), fmaxf(smax[2], smax[3]));

    const float elv = el_t[(size_t)bh * Nq + i0 + l15];
    const float xm  = elv + emax;
    const float m0  = fmaxf(xm, NEG * xm);     // safe shift: s - m <= 0
    const float c1  = elv - m0, c2 = NEG * elv - m0;

    const float*        erp = er_t + (size_t)bh * Nq;                    // + s*32
    const ushort*       vp  = Vfrag + (size_t)bh * 131072 + lane * 8;    // + s*2048
    const unsigned int* e0p = ebT + (size_t)b * 64 * Nq + i0 + l15;      // + s*Nq

    f32x4 zero4 = {0.f, 0.f, 0.f, 0.f};
    f32x4 acc[4] = {zero4, zero4, zero4, zero4};
    float l0 = 0.f;

    for (int s = 0; s < 64; s++) {
        short8 vb0 = *(const short8*)(vp + s * 2048);
        short8 vb1 = *(const short8*)(vp + s * 2048 + 512);
        short8 vb2 = *(const short8*)(vp + s * 2048 + 1024);
        short8 vb3 = *(const short8*)(vp + s * 2048 + 1536);
        unsigned int w0 = e0p[(size_t)s * Nq];
        float4 ea  = *(const float4*)(erp + s * 32 + quad * 8);
        float4 ebv = *(const float4*)(erp + s * 32 + quad * 8 + 4);

        const unsigned int wq0 = w0 >> (quad * 8);
        float er8[8] = {ea.x, ea.y, ea.z, ea.w, ebv.x, ebv.y, ebv.z, ebv.w};
        unsigned int u0[8];
#pragma unroll
        for (int jj = 0; jj < 8; jj++) {
            float e  = er8[jj];
            float t0 = fmaxf(e + c1, fmaf(NEG, e, c2));
            float x0 = __expf(t0);
            int k0 = ((int)(wq0 << (31 - jj))) >> 31;
            u0[jj] = __float_as_uint(x0) & (unsigned int)k0;
            l0 += __uint_as_float(u0[jj]);
        }
        union { short8 s8; unsigned int w[4]; } af0;
        af0.w[0] = __builtin_amdgcn_perm(u0[1], u0[0], 0x07060302);
        af0.w[1] = __builtin_amdgcn_perm(u0[3], u0[2], 0x07060302);
        af0.w[2] = __builtin_amdgcn_perm(u0[5], u0[4], 0x07060302);
        af0.w[3] = __builtin_amdgcn_perm(u0[7], u0[6], 0x07060302);

        acc[0] = __builtin_amdgcn_mfma_f32_16x16x32_bf16(af0.s8, vb0, acc[0], 0, 0, 0);
        acc[1] = __builtin_amdgcn_mfma_f32_16x16x32_bf16(af0.s8, vb1, acc[1], 0, 0, 0);
        acc[2] = __builtin_amdgcn_mfma_f32_16x16x32_bf16(af0.s8, vb2, acc[2], 0, 0, 0);
        acc[3] = __builtin_amdgcn_mfma_f32_16x16x32_bf16(af0.s8, vb3, acc[3], 0, 0, 0);
    }

    // ---- per-wave l reduction + write (no LDS, no idle waves) ----
    l0 += __shfl_xor(l0, 16, 64);
    l0 += __shfl_xor(l0, 32, 64);
    float lr[4];
#pragma unroll
    for (int r = 0; r < 4; r++) lr[r] = __shfl(l0, quad * 4 + r, 64);

#pragma unroll
    for (int nf = 0; nf < 4; nf++)
#pragma unroll
        for (int r = 0; r < 4; r++)
            attn[(((size_t)b * Nq + i0 + quad * 4 + r) * Hq + h) * Fq + nf * 16 + l15] =
                acc[nf][r] / lr[r];
}

// ---------------------------------------------------------------------------
// Kernel 4: out[b,i,f] = sigmoid( mean_h attn[b,i,h,f] )
// ---------------------------------------------------------------------------
__global__ __launch_bounds__(256) void out_kernel(
    const float* __restrict__ attn, float* __restrict__ out)
{
    const int idx = blockIdx.x * 256 + threadIdx.x;
    const int f   = idx & 63;
    const int bn  = idx >> 6;
    const float* p = attn + (size_t)bn * Hq * Fq + f;
    float s = 0.f;
#pragma unroll
    for (int h = 0; h < Hq; h++) s += p[h * Fq];
    s *= (1.f / Hq);
    out[idx] = 1.f / (1.f + __expf(-s));
}

// ---------------------------------------------------------------------------
extern "C" void kernel_launch(void* const* d_in, const int* in_sizes, int n_in,
                              void* d_out, int out_size, void* d_ws, size_t ws_size,
                              hipStream_t stream) {
    const float* nodes = (const float*)d_in[0];   // (2,2048,512)
    const int*   edges = (const int*)d_in[1];     // (2,2048,2048,1)
    const float* W     = (const float*)d_in[2];   // (512,512)
    const float* a     = (const float*)d_in[3];   // (128,)
    float* out = (float*)d_out;                   // (2,2048,64)

    char* ws = (char*)d_ws;
    ushort* Afrag = (ushort*)ws;           ws += (size_t)Bq * Nq * DIN * 2;           // 4 MB
    ushort* Wfrag = (ushort*)ws;           ws += (size_t)DIN * Hq * Fq * 2;           // 512 KB
    ushort* Vfrag = (ushort*)ws;           ws += (size_t)Bq * Hq * Nq * Fq * 2;       // 4 MB
    float*  el_t  = (float*)ws;            ws += (size_t)Bq * Hq * Nq * 4;            // 128 KB
    float*  er_t  = (float*)ws;            ws += (size_t)Bq * Hq * Nq * 4;            // 128 KB
    unsigned int* ebT = (unsigned int*)ws; ws += (size_t)Bq * (Nq / 32) * Nq * 4;     // 1 MB
    float*  attn  = (float*)ws;                                                       // 16 MB

    prep_kernel<<<AFRAG_BLOCKS + WFRAG_BLOCKS, 256, 0, stream>>>(nodes, Afrag, W, Wfrag);
    work_kernel<<<GEMM_BLOCKS + PACK_BLOCKS, 256, 0, stream>>>(
        Afrag, Wfrag, a, Vfrag, el_t, er_t, edges, ebT);
    attn_kernel<<<Bq * Hq * (Nq / 64), 256, 0, stream>>>(el_t, er_t, Vfrag, ebT, attn);
    out_kernel<<<(Bq * Nq * Fq) / 256, 256, 0, stream>>>(attn, out);
}

// Round 11
// 124.595 us; speedup vs baseline: 1.0533x; 1.0533x over previous
//
#include <hip/hip_runtime.h>
#include <hip/hip_bf16.h>
#include <math.h>

// Problem constants (B, N, D_IN, H, F) = (2, 2048, 512, 8, 64)
#define Bq   2
#define Nq   2048
#define DIN  512
#define Hq   8
#define Fq   64
#define NEG  0.2f

using short8 = __attribute__((ext_vector_type(8))) short;   // 8 bf16 (4 VGPRs)
using f32x4  = __attribute__((ext_vector_type(4))) float;   // MFMA C/D

__device__ inline unsigned int bf16_rne(float x) {
    unsigned int u = __float_as_uint(x);
    u += 0x7fffu + ((u >> 16) & 1u);
    return u >> 16;
}

// ---------------------------------------------------------------------------
// Kernel 1 (prep): afrag (256 blocks) + wfrag (128 blocks), R8-R10-validated.
// ---------------------------------------------------------------------------
#define AFRAG_BLOCKS 256
#define WFRAG_BLOCKS 128

__global__ __launch_bounds__(256) void prep_kernel(
    const float* __restrict__ nodes, ushort* __restrict__ Afrag,
    const float* __restrict__ W,     ushort* __restrict__ Wfrag)
{
    __shared__ __align__(16) char smem[16 * 516 * 4];   // 33 KB: max(As, Ws)
    const int bid = blockIdx.x;
    const int t   = threadIdx.x;

    if (bid < AFRAG_BLOCKS) {
        float (*As)[516] = (float(*)[516])smem;
        const int mt = bid;
        {
            const int row = t >> 4, c = t & 15;
#pragma unroll
            for (int i = 0; i < 8; i++) {
                float4 v = *(const float4*)&nodes[((size_t)mt * 16 + row) * DIN + (c + i * 16) * 4];
                *(float4*)&As[row][(c + i * 16) * 4] = v;
            }
        }
        __syncthreads();
        const int lane = t & 63, ksg = t >> 6;
        const int quad = lane >> 4, l15 = lane & 15;
#pragma unroll
        for (int k2 = 0; k2 < 4; k2++) {
            int ks = ksg * 4 + k2;
            const float* src = &As[l15][ks * 32 + quad * 8];
            float4 f0 = *(const float4*)src;
            float4 f1 = *(const float4*)(src + 4);
            uint4 pk;
            pk.x = bf16_rne(f0.x) | (bf16_rne(f0.y) << 16);
            pk.y = bf16_rne(f0.z) | (bf16_rne(f0.w) << 16);
            pk.z = bf16_rne(f1.x) | (bf16_rne(f1.y) << 16);
            pk.w = bf16_rne(f1.z) | (bf16_rne(f1.w) << 16);
            *(uint4*)(Afrag + ((size_t)(mt * 16 + ks) * 64 + lane) * 8) = pk;
        }
        return;
    }

    {
        float (*Ws)[68] = (float(*)[68])smem;
        const int id = bid - AFRAG_BLOCKS;
        const int ks = id & 15, h = id >> 4;
        {
            const int row = t >> 3, c = t & 7;
            const float* src = &W[(size_t)(ks * 32 + row) * (Hq * Fq) + h * 64 + c * 8];
            float4 v0 = *(const float4*)src;
            float4 v1 = *(const float4*)(src + 4);
            *(float4*)&Ws[row][c * 8]     = v0;
            *(float4*)&Ws[row][c * 8 + 4] = v1;
        }
        __syncthreads();
        const int lane = t & 63, nf = t >> 6;
        const int quad = lane >> 4, l15 = lane & 15;
        float f[8];
#pragma unroll
        for (int jj = 0; jj < 8; jj++) f[jj] = Ws[quad * 8 + jj][nf * 16 + l15];
        uint4 pk;
        pk.x = bf16_rne(f[0]) | (bf16_rne(f[1]) << 16);
        pk.y = bf16_rne(f[2]) | (bf16_rne(f[3]) << 16);
        pk.z = bf16_rne(f[4]) | (bf16_rne(f[5]) << 16);
        pk.w = bf16_rne(f[6]) | (bf16_rne(f[7]) << 16);
        *(uint4*)(Wfrag + (((size_t)(h * 16 + ks) * 4 + nf) * 64 + lane) * 8) = pk;
    }
}

// ---------------------------------------------------------------------------
// Kernel 2 (work): gemm (blocks [0,512)) + pack_edges (int4 MLP) — R9/R10-validated.
// ---------------------------------------------------------------------------
#define GEMM_BLOCKS 512
#define PACK_BLOCKS 1024   // B * 64 words * 2048 rows / 256 threads

__global__ __launch_bounds__(256) void work_kernel(
    const ushort* __restrict__ Afrag, const ushort* __restrict__ Wfrag,
    const float*  __restrict__ avec,
    ushort* __restrict__ Vfrag,      // [16 bh][64 s][4 nf][64 lane][8] bf16
    float* __restrict__ el_t,        // [16][2048]
    float* __restrict__ er_t,        // [16][2048]
    const int* __restrict__ edges, unsigned int* __restrict__ ebT)
{
    const int bid = blockIdx.x;
    const int t   = threadIdx.x;

    if (bid >= GEMM_BLOCKS) {
        // ---- pack edges -> transposed bitmask ebT[b][jword(64)][i(2048)] ----
        int gid = (bid - GEMM_BLOCKS) * 256 + t;   // 0..262143
        int i = gid & 2047;
        int w = (gid >> 11) & 63;
        int b = gid >> 17;
        const int4* ep = (const int4*)(edges + (((size_t)b * Nq + i) * Nq + w * 32));
        unsigned int word = 0;
#pragma unroll
        for (int c = 0; c < 8; c++) {
            int4 v = ep[c];
            word |= (v.x != 0 ? 1u : 0u) << (c * 4);
            word |= (v.y != 0 ? 1u : 0u) << (c * 4 + 1);
            word |= (v.z != 0 ? 1u : 0u) << (c * 4 + 2);
            word |= (v.w != 0 ? 1u : 0u) << (c * 4 + 3);
        }
        ebT[((size_t)b * 64 + w) * Nq + i] = word;
        return;
    }

    // ---- gemm: R8-R10-validated body ----
    const int lane = t & 63;
    const int wv   = t >> 6;
    const int quad = lane >> 4;
    const int l15  = lane & 15;
    const int h    = bid >> 6;            // 0..7
    const int mt   = (bid & 63) * 4 + wv; // 0..255
    const int row0 = mt * 16;

    const ushort* ap = Afrag + (size_t)mt * 8192 + lane * 8;   // + ks*512
    const ushort* bp = Wfrag + (size_t)h * 32768 + lane * 8;   // + ks*2048 + nf*512

    f32x4 zero4 = {0.f, 0.f, 0.f, 0.f};
    f32x4 acc[4] = {zero4, zero4, zero4, zero4};

    short8 a0, a1, b0[4], b1[4];
    a0 = *(const short8*)(ap);
#pragma unroll
    for (int nf = 0; nf < 4; nf++) b0[nf] = *(const short8*)(bp + nf * 512);

    for (int ks = 0; ks < 16; ks += 2) {
        a1 = *(const short8*)(ap + (ks + 1) * 512);
#pragma unroll
        for (int nf = 0; nf < 4; nf++) b1[nf] = *(const short8*)(bp + (ks + 1) * 2048 + nf * 512);
#pragma unroll
        for (int nf = 0; nf < 4; nf++)
            acc[nf] = __builtin_amdgcn_mfma_f32_16x16x32_bf16(a0, b0[nf], acc[nf], 0, 0, 0);
        a0 = *(const short8*)(ap + (ks + 2) * 512);   // ks=14 -> past end: lands in Wfrag, unused
#pragma unroll
        for (int nf = 0; nf < 4; nf++) b0[nf] = *(const short8*)(bp + (ks + 2) * 2048 + nf * 512);
#pragma unroll
        for (int nf = 0; nf < 4; nf++)
            acc[nf] = __builtin_amdgcn_mfma_f32_16x16x32_bf16(a1, b1[nf], acc[nf], 0, 0, 0);
    }

    // ---- fused el/er ----
    float aL[4], aR[4];
#pragma unroll
    for (int nf = 0; nf < 4; nf++) {
        aL[nf] = avec[nf * 16 + l15];
        aR[nf] = avec[Fq + nf * 16 + l15];
    }
    const int bb = row0 >> 11;
    const int bh = bb * Hq + h;
#pragma unroll
    for (int r = 0; r < 4; r++) {
        float pl = acc[0][r] * aL[0] + acc[1][r] * aL[1] + acc[2][r] * aL[2] + acc[3][r] * aL[3];
        float pr = acc[0][r] * aR[0] + acc[1][r] * aR[1] + acc[2][r] * aR[2] + acc[3][r] * aR[3];
#pragma unroll
        for (int off = 1; off < 16; off <<= 1) {
            pl += __shfl_xor(pl, off, 64);
            pr += __shfl_xor(pr, off, 64);
        }
        if (l15 == 0) {
            int n = (row0 + quad * 4 + r) & (Nq - 1);
            el_t[(size_t)bh * Nq + n] = pl;
            er_t[(size_t)bh * Nq + n] = pr;
        }
    }

    // ---- Vfrag: C in attn B-fragment order (validated R3..R10) ----
    const int n_base = row0 & (Nq - 1);
    const int sblk   = n_base >> 5;
    const int quadp  = ((wv & 1) << 1) | (quad >> 1);
    const int jj0    = (quad & 1) * 4;
#pragma unroll
    for (int nf = 0; nf < 4; nf++) {
        unsigned int r0 = bf16_rne(acc[nf][0]), r1 = bf16_rne(acc[nf][1]);
        unsigned int r2 = bf16_rne(acc[nf][2]), r3 = bf16_rne(acc[nf][3]);
        uint2 pk;
        pk.x = r0 | (r1 << 16);
        pk.y = r2 | (r3 << 16);
        size_t off = ((((size_t)bh * 64 + sblk) * 4 + nf) * 64 + quadp * 16 + l15) * 8 + jj0;
        *(uint2*)(Vfrag + off) = pk;
    }
}

// ---------------------------------------------------------------------------
// Kernel 3: MFMA attention. R10 coverage (512 blocks, 64 rows/block) but
// 512-thread blocks = 8 waves: 4 row-groups x 2 K-halves (in-block K-split-2).
// Rationale: R10 had 2048 waves = 2 waves/SIMD -> latency-bound (~30 us vs
// ~10 us floor). Split-2 doubles to 4 waves/SIMD; V-stream still shared by
// the 4 row-group waves per half (L2 traffic unchanged). LDS combine pairs.
// exp via exp2 with 1/ln2 folded into constants (saves 8 v_mul/step).
// ---------------------------------------------------------------------------
__global__ __launch_bounds__(512) void attn_kernel(
    const float* __restrict__ el_t, const float* __restrict__ er_t,
    const ushort* __restrict__ Vfrag,
    const unsigned int* __restrict__ ebT, float* __restrict__ attn)
{
    const int lane = threadIdx.x & 63;
    const int wv8  = threadIdx.x >> 6;     // 0..7
    const int rg   = wv8 & 3;              // row-group
    const int kh   = wv8 >> 2;             // j-half 0/1
    const int quad = lane >> 4;
    const int l15  = lane & 15;
    const int bid  = blockIdx.x;           // 512 = B*H*32
    const int it   = bid & 31;
    const int h    = (bid >> 5) & 7;
    const int b    = bid >> 8;
    const int bh   = b * Hq + h;
    const int i0   = it * 64 + rg * 16;    // this wave's 16 rows

    // ---- block-wide ermax over er_t[bh][:] ----
    __shared__ float smax[8];
    const float* errow = er_t + (size_t)bh * Nq;
    float mx = -INFINITY;
#pragma unroll
    for (int ii = 0; ii < 4; ii++) mx = fmaxf(mx, errow[threadIdx.x + ii * 512]);
#pragma unroll
    for (int off = 32; off > 0; off >>= 1) mx = fmaxf(mx, __shfl_xor(mx, off, 64));
    if (lane == 0) smax[wv8] = mx;
    __syncthreads();
    float emax = smax[0];
#pragma unroll
    for (int q = 1; q < 8; q++) emax = fmaxf(emax, smax[q]);

    const float elv = el_t[(size_t)bh * Nq + i0 + l15];
    const float xm  = elv + emax;
    const float m0  = fmaxf(xm, NEG * xm);       // safe shift: s - m <= 0
    const float R   = 1.4426950408889634f;       // 1/ln2
    const float R2  = NEG * R;
    const float c1  = (elv - m0) * R, c2 = (NEG * elv - m0) * R;

    const float*        erp = er_t + (size_t)bh * Nq;                    // + s*32
    const ushort*       vp  = Vfrag + (size_t)bh * 131072 + lane * 8;    // + s*2048
    const unsigned int* e0p = ebT + (size_t)b * 64 * Nq + i0 + l15;      // + s*Nq

    f32x4 zero4 = {0.f, 0.f, 0.f, 0.f};
    f32x4 acc[4] = {zero4, zero4, zero4, zero4};
    float l0 = 0.f;

    const int s_beg = kh * 32, s_end = kh * 32 + 32;
    for (int s = s_beg; s < s_end; s++) {
        short8 vb0 = *(const short8*)(vp + s * 2048);
        short8 vb1 = *(const short8*)(vp + s * 2048 + 512);
        short8 vb2 = *(const short8*)(vp + s * 2048 + 1024);
        short8 vb3 = *(const short8*)(vp + s * 2048 + 1536);
        unsigned int w0 = e0p[(size_t)s * Nq];
        float4 ea  = *(const float4*)(erp + s * 32 + quad * 8);
        float4 ebv = *(const float4*)(erp + s * 32 + quad * 8 + 4);

        const unsigned int wq0 = w0 >> (quad * 8);
        float er8[8] = {ea.x, ea.y, ea.z, ea.w, ebv.x, ebv.y, ebv.z, ebv.w};
        unsigned int u0[8];
#pragma unroll
        for (int jj = 0; jj < 8; jj++) {
            float e  = er8[jj];
            float t0 = fmaxf(fmaf(R, e, c1), fmaf(R2, e, c2));
            float x0 = __builtin_amdgcn_exp2f(t0);
            int k0 = ((int)(wq0 << (31 - jj))) >> 31;
            u0[jj] = __float_as_uint(x0) & (unsigned int)k0;
            l0 += __uint_as_float(u0[jj]);
        }
        union { short8 s8; unsigned int w[4]; } af0;
        af0.w[0] = __builtin_amdgcn_perm(u0[1], u0[0], 0x07060302);
        af0.w[1] = __builtin_amdgcn_perm(u0[3], u0[2], 0x07060302);
        af0.w[2] = __builtin_amdgcn_perm(u0[5], u0[4], 0x07060302);
        af0.w[3] = __builtin_amdgcn_perm(u0[7], u0[6], 0x07060302);

        acc[0] = __builtin_amdgcn_mfma_f32_16x16x32_bf16(af0.s8, vb0, acc[0], 0, 0, 0);
        acc[1] = __builtin_amdgcn_mfma_f32_16x16x32_bf16(af0.s8, vb1, acc[1], 0, 0, 0);
        acc[2] = __builtin_amdgcn_mfma_f32_16x16x32_bf16(af0.s8, vb2, acc[2], 0, 0, 0);
        acc[3] = __builtin_amdgcn_mfma_f32_16x16x32_bf16(af0.s8, vb3, acc[3], 0, 0, 0);
    }

    // ---- combine the two K-halves via LDS ----
    __shared__ __align__(16) float lds_acc[4][16][65];
    __shared__ float lds_l[4][64];
    if (kh == 1) {
#pragma unroll
        for (int nf = 0; nf < 4; nf++)
#pragma unroll
            for (int r = 0; r < 4; r++)
                lds_acc[rg][quad * 4 + r][nf * 16 + l15] = acc[nf][r];
        lds_l[rg][lane] = l0;
    }
    __syncthreads();
    if (kh == 0) {
#pragma unroll
        for (int nf = 0; nf < 4; nf++)
#pragma unroll
            for (int r = 0; r < 4; r++)
                acc[nf][r] += lds_acc[rg][quad * 4 + r][nf * 16 + l15];
        l0 += lds_l[rg][lane];
        l0 += __shfl_xor(l0, 16, 64);
        l0 += __shfl_xor(l0, 32, 64);
        float lr[4];
#pragma unroll
        for (int r = 0; r < 4; r++) lr[r] = __shfl(l0, quad * 4 + r, 64);

#pragma unroll
        for (int nf = 0; nf < 4; nf++)
#pragma unroll
            for (int r = 0; r < 4; r++)
                attn[(((size_t)b * Nq + i0 + quad * 4 + r) * Hq + h) * Fq + nf * 16 + l15] =
                    acc[nf][r] / lr[r];
    }
}

// ---------------------------------------------------------------------------
// Kernel 4: out[b,i,f] = sigmoid( mean_h attn[b,i,h,f] )
// ---------------------------------------------------------------------------
__global__ __launch_bounds__(256) void out_kernel(
    const float* __restrict__ attn, float* __restrict__ out)
{
    const int idx = blockIdx.x * 256 + threadIdx.x;
    const int f   = idx & 63;
    const int bn  = idx >> 6;
    const float* p = attn + (size_t)bn * Hq * Fq + f;
    float s = 0.f;
#pragma unroll
    for (int h = 0; h < Hq; h++) s += p[h * Fq];
    s *= (1.f / Hq);
    out[idx] = 1.f / (1.f + __expf(-s));
}

// ---------------------------------------------------------------------------
extern "C" void kernel_launch(void* const* d_in, const int* in_sizes, int n_in,
                              void* d_out, int out_size, void* d_ws, size_t ws_size,
                              hipStream_t stream) {
    const float* nodes = (const float*)d_in[0];   // (2,2048,512)
    const int*   edges = (const int*)d_in[1];     // (2,2048,2048,1)
    const float* W     = (const float*)d_in[2];   // (512,512)
    const float* a     = (const float*)d_in[3];   // (128,)
    float* out = (float*)d_out;                   // (2,2048,64)

    char* ws = (char*)d_ws;
    ushort* Afrag = (ushort*)ws;           ws += (size_t)Bq * Nq * DIN * 2;           // 4 MB
    ushort* Wfrag = (ushort*)ws;           ws += (size_t)DIN * Hq * Fq * 2;           // 512 KB
    ushort* Vfrag = (ushort*)ws;           ws += (size_t)Bq * Hq * Nq * Fq * 2;       // 4 MB
    float*  el_t  = (float*)ws;            ws += (size_t)Bq * Hq * Nq * 4;            // 128 KB
    float*  er_t  = (float*)ws;            ws += (size_t)Bq * Hq * Nq * 4;            // 128 KB
    unsigned int* ebT = (unsigned int*)ws; ws += (size_t)Bq * (Nq / 32) * Nq * 4;     // 1 MB
    float*  attn  = (float*)ws;                                                       // 16 MB

    prep_kernel<<<AFRAG_BLOCKS + WFRAG_BLOCKS, 256, 0, stream>>>(nodes, Afrag, W, Wfrag);
    work_kernel<<<GEMM_BLOCKS + PACK_BLOCKS, 256, 0, stream>>>(
        Afrag, Wfrag, a, Vfrag, el_t, er_t, edges, ebT);
    attn_kernel<<<Bq * Hq * (Nq / 64), 512, 0, stream>>>(el_t, er_t, Vfrag, ebT, attn);
    out_kernel<<<(Bq * Nq * Fq) / 256, 256, 0, stream>>>(attn, out);
}